// Round 9
// baseline (700.682 us; speedup 1.0000x reference)
//
#include <hip/hip_runtime.h>

// ContinuousFilterConvolution (SchNet CFConv), MI355X gfx950.
// V=50000, E=1600000, DH=128, NB=16. fp32 in/out.
// Round 9 = round 8 resubmitted (GPU acquisition timeout, no verdict).
// Round 8: phase-1 (rbf@W1) moved to MFMA (K zero-padded 16->32, same
// verified 16x16x32_f16 layouts); rbf computed once (2 exp/thread) into a
// 48B-stride LDS buffer; W1^T fragments in registers (loaded once/block).
// Barrier count 3->2 per tile via double-buffered sSrc/sDst.
// Rationale: r7 counters: VALUBusy 46% with MfmaUtil 5% -> phase-1 scalar
// W1 matmul (~60% of VALU issue) ran on VALU while matrix pipe idled.

#define DHID 128
#define NBASE 16

constexpr int TE = 128;        // edges per tile
constexpr int THREADS = 1024;  // 16 waves

using f16x8 = __fp16 __attribute__((ext_vector_type(8)));
using f16x4 = __fp16 __attribute__((ext_vector_type(4)));
using f32x4 = float __attribute__((ext_vector_type(4)));

// ---------------- sort-by-dest machinery (rebuilt every launch) ----------------

__global__ void zero_kernel(float4* __restrict__ out4, int n4,
                            int* __restrict__ cursor, int V) {
    for (int i = blockIdx.x * blockDim.x + threadIdx.x; i < n4;
         i += gridDim.x * blockDim.x)
        out4[i] = make_float4(0.f, 0.f, 0.f, 0.f);
    for (int i = blockIdx.x * blockDim.x + threadIdx.x; i < V;
         i += gridDim.x * blockDim.x)
        cursor[i] = 0;
}

__global__ void hist_kernel(const int* __restrict__ dstI, int E,
                            int* __restrict__ cursor) {
    for (int i = blockIdx.x * blockDim.x + threadIdx.x; i < E;
         i += gridDim.x * blockDim.x)
        atomicAdd(&cursor[dstI[i]], 1);
}

constexpr int SCAN_BS = 256;

__global__ __launch_bounds__(SCAN_BS)
void scan_partial(const int* __restrict__ cursor, int V, int* __restrict__ sums) {
    const int i = blockIdx.x * SCAN_BS + threadIdx.x;
    int v = (i < V) ? cursor[i] : 0;
#pragma unroll
    for (int off = 32; off; off >>= 1) v += __shfl_down(v, off, 64);
    __shared__ int ws[4];
    if ((threadIdx.x & 63) == 0) ws[threadIdx.x >> 6] = v;
    __syncthreads();
    if (threadIdx.x == 0) sums[blockIdx.x] = ws[0] + ws[1] + ws[2] + ws[3];
}

// apply: each block redundantly scans sums[0..nch) (tiny), then scans its chunk
__global__ __launch_bounds__(SCAN_BS)
void scan_apply(int* __restrict__ cursor, int V,
                const int* __restrict__ sums, int nch) {
    __shared__ int sIncl[SCAN_BS];
    __shared__ int wt[4];
    const int tid = threadIdx.x, lane = tid & 63, w = tid >> 6;
    // block-wide inclusive scan of sums
    {
        const int v = (tid < nch) ? sums[tid] : 0;
        int s = v;
#pragma unroll
        for (int off = 1; off < 64; off <<= 1) {
            const int n = __shfl_up(s, off, 64);
            if (lane >= off) s += n;
        }
        if (lane == 63) wt[w] = s;
        __syncthreads();
        int wo = 0;
        for (int j = 0; j < w; ++j) wo += wt[j];
        sIncl[tid] = wo + s;
        __syncthreads();
    }
    const int base = blockIdx.x ? sIncl[blockIdx.x - 1] : 0;
    __syncthreads();  // wt reuse below
    // per-element exclusive scan of this chunk
    const int i = blockIdx.x * SCAN_BS + tid;
    const int val = (i < V) ? cursor[i] : 0;
    int s = val;
#pragma unroll
    for (int off = 1; off < 64; off <<= 1) {
        const int n = __shfl_up(s, off, 64);
        if (lane >= off) s += n;
    }
    if (lane == 63) wt[w] = s;
    __syncthreads();
    int wo = 0;
    for (int j = 0; j < w; ++j) wo += wt[j];
    if (i < V) cursor[i] = base + wo + s - val;  // exclusive = bucket start
}

__global__ void scatter_kernel(const int* __restrict__ dstI, int E,
                               int* __restrict__ cursor, int* __restrict__ perm) {
    for (int i = blockIdx.x * blockDim.x + threadIdx.x; i < E;
         i += gridDim.x * blockDim.x) {
        const int pos = atomicAdd(&cursor[dstI[i]], 1);
        perm[pos] = i;
    }
}

// ---------------- fused CFConv, all-MFMA, in-register segmented flush ----------------

__global__ __launch_bounds__(THREADS, 8)
void cfconv_mfma(const float* __restrict__ node_feats,
                 const float* __restrict__ coords,
                 const int* __restrict__ srcI,
                 const int* __restrict__ dstI,
                 const float* __restrict__ W1,
                 const float* __restrict__ W2,
                 const int* __restrict__ perm,
                 float* __restrict__ out,
                 int E, int ntiles)
{
    // XOR-swizzle on 16B granules for m1/W2: byte ^= (row&7)<<4  (T2; G4)
    __shared__ __align__(16) unsigned short sM1h[TE * DHID];   // f16 m1 [e][k], 32 KB
    __shared__ __align__(16) unsigned short sW2t[DHID * DHID]; // f16 W2^T [c][k], 32 KB
    __shared__ __align__(16) unsigned int sRbf[TE * 12];       // f16 rbf, 48B rows, 6 KB
    __shared__ int sSrc[2][TE];   // double-buffered (replaces barrier A)
    __shared__ int sDst[2][TE];

    const int tid = threadIdx.x;
    const int lane = tid & 63;
    const int w = tid >> 6;      // wave 0..15

    // ---- stage W2^T as f16, swizzled (once per block)
    {
        const int c = tid & 127;
        const int kq = (tid >> 7) * 16;
        f16x8 lo, hi;
#pragma unroll
        for (int i = 0; i < 8; ++i) {
            lo[i] = (__fp16)W2[(kq + i) * DHID + c];
            hi[i] = (__fp16)W2[(kq + 8 + i) * DHID + c];
        }
        char* base = (char*)sW2t + c * 256;
        const int sw = (c & 7) << 4;
        *(f16x8*)(base + ((kq * 2) ^ sw)) = lo;
        *(f16x8*)(base + ((kq * 2 + 16) ^ sw)) = hi;
    }

    const int e1 = tid & 127;    // phase-1a edge
    const int kg = tid >> 7;     // phase-1a basis pair (b = 2kg, 2kg+1)
    const int l15 = lane & 15;
    const int lg = lane >> 4;    // 0..3
    // phase-1b: wave -> k-tile kt (8), edge-tile group etb (2x4)
    const int kt = w >> 1;
    const int etb = (w & 1) * 4;
    // phase-2: wave -> 32 edges x 32 channels quadrant
    const int er = (w >> 2) * 32;
    const int cb = (w & 3) * 32;

    // ---- W1^T A-fragments in registers (once per block). K padded 16->32:
    // lanes lg>=2 supply k=16..31 with A=0 -> B garbage there is harmless.
    f16x8 w1f;
    {
        const int k = kt * 16 + l15;
#pragma unroll
        for (int j = 0; j < 8; ++j) {
            const float v = W1[((lg & 1) * 8 + j) * DHID + k];  // always in-bounds
            w1f[j] = (lg < 2) ? (__fp16)v : (__fp16)0.f;
        }
    }

    constexpr float WIDTH = 4.5f / 15.0f;
    constexpr float COEFF = -0.5f / (WIDTH * WIDTH);

    int pbuf = 0;
    for (int tile = blockIdx.x; tile < ntiles; tile += gridDim.x) {
        const int ebase = tile * TE;

        // ---- phase 1a: rbf pair per thread -> sRbf (f16x2 packed)
        {
            int ge = ebase + e1;
            if (ge >= E) ge = E - 1;  // never triggers (E % TE == 0)
            const int pe = perm[ge];
            const int s = srcI[pe];
            const int dv = dstI[pe];
            if (kg == 0) { sSrc[pbuf][e1] = s; sDst[pbuf][e1] = dv; }
            const float dx = coords[s * 3 + 0] - coords[dv * 3 + 0];
            const float dy = coords[s * 3 + 1] - coords[dv * 3 + 1];
            const float dz = coords[s * 3 + 2] - coords[dv * 3 + 2];
            const float d = sqrtf(fmaf(dx, dx, fmaf(dy, dy, dz * dz)));
            const float t0 = d - WIDTH * (float)(2 * kg);
            const float t1 = d - WIDTH * (float)(2 * kg + 1);
            union { __fp16 h[2]; unsigned int u; } pk;
            pk.h[0] = (__fp16)__expf(COEFF * t0 * t0);
            pk.h[1] = (__fp16)__expf(COEFF * t1 * t1);
            sRbf[e1 * 12 + kg] = pk.u;   // 48B row stride -> bank spread
        }
        __syncthreads();  // (B1)

        // ---- phase 1b: m1^T = relu(W1^T_pad @ rbf^T_pad) via MFMA -> sM1h
        {
#pragma unroll
            for (int i = 0; i < 4; ++i) {
                const int e = (etb + i) * 16 + l15;
                // B-frag: rbf[e][b=lg*8+j]; lg>=2 reads lg&1 slot (A=0 there)
                const f16x8 bf =
                    *(const f16x8*)((const char*)sRbf + e * 48 + (lg & 1) * 16);
                f32x4 d4 = {0.f, 0.f, 0.f, 0.f};
                d4 = __builtin_amdgcn_mfma_f32_16x16x32_f16(w1f, bf, d4, 0, 0, 0);
                // D: col=l15 -> e, row=lg*4+r -> k rel; write 4 consecutive k
                f16x4 hv;
#pragma unroll
                for (int r = 0; r < 4; ++r) hv[r] = (__fp16)fmaxf(d4[r], 0.f);
                char* p = (char*)sM1h + e * 256 + ((kt * 32 + lg * 8) ^ ((e & 7) << 4));
                *(f16x4*)p = hv;
            }
        }
        __syncthreads();  // (B2)

        // ---- phase 2: swapped MFMA. q = W2^T(c x k) · m1^T(k x e)
        f32x4 q00 = {0.f,0.f,0.f,0.f};
        f32x4 q01 = {0.f,0.f,0.f,0.f};
        f32x4 q10 = {0.f,0.f,0.f,0.f};
        f32x4 q11 = {0.f,0.f,0.f,0.f};
        {
            const int ra0 = er + l15, ra1 = er + 16 + l15;       // edge rows
            const int rb0 = cb + l15, rb1 = cb + 16 + l15;       // channel rows
            const char* pa0 = (const char*)sM1h + ra0 * 256;
            const char* pa1 = (const char*)sM1h + ra1 * 256;
            const char* pb0 = (const char*)sW2t + rb0 * 256;
            const char* pb1 = (const char*)sW2t + rb1 * 256;
            const int sa0 = (ra0 & 7) << 4, sa1 = (ra1 & 7) << 4;
            const int sb0 = (rb0 & 7) << 4, sb1 = (rb1 & 7) << 4;
#pragma unroll
            for (int kb = 0; kb < 4; ++kb) {
                const int kbyte = kb * 64 + lg * 16;
                const f16x8 a0 = *(const f16x8*)(pa0 + (kbyte ^ sa0));
                const f16x8 a1 = *(const f16x8*)(pa1 + (kbyte ^ sa1));
                const f16x8 b0 = *(const f16x8*)(pb0 + (kbyte ^ sb0));
                const f16x8 b1 = *(const f16x8*)(pb1 + (kbyte ^ sb1));
                q00 = __builtin_amdgcn_mfma_f32_16x16x32_f16(b0, a0, q00, 0, 0, 0);
                q01 = __builtin_amdgcn_mfma_f32_16x16x32_f16(b0, a1, q01, 0, 0, 0);
                q10 = __builtin_amdgcn_mfma_f32_16x16x32_f16(b1, a0, q10, 0, 0, 0);
                q11 = __builtin_amdgcn_mfma_f32_16x16x32_f16(b1, a1, q11, 0, 0, 0);
            }
        }

        // ---- epilogue: relu * node_feats gather, in-register segmented flush
#pragma unroll
        for (int ti = 0; ti < 2; ++ti) {
            const int e = er + ti * 16 + l15;
            const int dv = sDst[pbuf][e];
            const int s = sSrc[pbuf][e];
            bool pr1, pr2, pr4, pr8;
            {
                int nd;
                nd = __shfl_up(dv, 1, 16); pr1 = (l15 >= 1) && (nd == dv);
                nd = __shfl_up(dv, 2, 16); pr2 = (l15 >= 2) && (nd == dv);
                nd = __shfl_up(dv, 4, 16); pr4 = (l15 >= 4) && (nd == dv);
                nd = __shfl_up(dv, 8, 16); pr8 = (l15 >= 8) && (nd == dv);
            }
            const int ndn = __shfl_down(dv, 1, 16);
            const bool tail = (l15 == 15) || (ndn != dv);
#pragma unroll
            for (int tj = 0; tj < 2; ++tj) {
                const f32x4 q = tj ? (ti ? q11 : q10) : (ti ? q01 : q00);
                const int c0 = cb + tj * 16 + lg * 4;
                const float4 nf = *(const float4*)&node_feats[(size_t)s * DHID + c0];
                float m0 = fmaxf(q[0], 0.f) * nf.x;
                float m1 = fmaxf(q[1], 0.f) * nf.y;
                float m2 = fmaxf(q[2], 0.f) * nf.z;
                float m3 = fmaxf(q[3], 0.f) * nf.w;
                float t0, t1, t2, t3;
                t0 = __shfl_up(m0, 1, 16); t1 = __shfl_up(m1, 1, 16);
                t2 = __shfl_up(m2, 1, 16); t3 = __shfl_up(m3, 1, 16);
                if (pr1) { m0 += t0; m1 += t1; m2 += t2; m3 += t3; }
                t0 = __shfl_up(m0, 2, 16); t1 = __shfl_up(m1, 2, 16);
                t2 = __shfl_up(m2, 2, 16); t3 = __shfl_up(m3, 2, 16);
                if (pr2) { m0 += t0; m1 += t1; m2 += t2; m3 += t3; }
                t0 = __shfl_up(m0, 4, 16); t1 = __shfl_up(m1, 4, 16);
                t2 = __shfl_up(m2, 4, 16); t3 = __shfl_up(m3, 4, 16);
                if (pr4) { m0 += t0; m1 += t1; m2 += t2; m3 += t3; }
                t0 = __shfl_up(m0, 8, 16); t1 = __shfl_up(m1, 8, 16);
                t2 = __shfl_up(m2, 8, 16); t3 = __shfl_up(m3, 8, 16);
                if (pr8) { m0 += t0; m1 += t1; m2 += t2; m3 += t3; }
                if (tail) {
                    float* op = &out[(size_t)dv * DHID + c0];
                    atomicAdd(op + 0, m0);
                    atomicAdd(op + 1, m1);
                    atomicAdd(op + 2, m2);
                    atomicAdd(op + 3, m3);
                }
            }
        }
        pbuf ^= 1;
    }
}

extern "C" void kernel_launch(void* const* d_in, const int* in_sizes, int n_in,
                              void* d_out, int out_size, void* d_ws, size_t ws_size,
                              hipStream_t stream) {
    const float* node_feats = (const float*)d_in[0];
    const float* coords     = (const float*)d_in[1];
    const int*   srcI       = (const int*)d_in[2];
    const int*   dstI       = (const int*)d_in[3];
    const float* W1         = (const float*)d_in[4];
    const float* W2         = (const float*)d_in[5];
    float* out = (float*)d_out;

    const int E = in_sizes[2];
    const int V = in_sizes[0] / DHID;

    // workspace: cursor[V], perm[E], sums[nch]  (~6.6 MB)
    int* cursor = (int*)d_ws;
    int* perm   = cursor + V;
    const int nch = (V + SCAN_BS - 1) / SCAN_BS;   // 196 <= 256
    int* sums   = perm + E;

    const int n4 = out_size / 4;
    zero_kernel<<<1024, 256, 0, stream>>>((float4*)out, n4, cursor, V);
    hist_kernel<<<2048, 256, 0, stream>>>(dstI, E, cursor);
    scan_partial<<<nch, SCAN_BS, 0, stream>>>(cursor, V, sums);
    scan_apply<<<nch, SCAN_BS, 0, stream>>>(cursor, V, sums, nch);
    scatter_kernel<<<2048, 256, 0, stream>>>(dstI, E, cursor, perm);

    const int ntiles = (E + TE - 1) / TE;
    const int grid = ntiles < 512 ? ntiles : 512;
    cfconv_mfma<<<grid, THREADS, 0, stream>>>(node_feats, coords, srcI, dstI,
                                              W1, W2, perm, out, E, ntiles);
}